// Round 6
// baseline (25.286 us; speedup 1.0000x reference)
//
#include <hip/hip_runtime.h>
#include <hip/hip_bf16.h>

#define Bc 32
#define Lc 2048
#define Hc 768
#define Dc 32
#define Cc 64
#define NT 4                    // quarter-clause tasks per clause
#define QROWS 16                // max rows per task
#define NTASK (Bc * Dc * NT)    // 4096

// K1: one wave (64 threads) per quarter-clause. Permuted task assignment
// decorrelates same-doc tasks across CUs; 4096 tasks of <=16 rows give a
// balanced static split (worst CU ~2x better than clause-per-block).
__global__ __launch_bounds__(64) void k1_partial(
    const float* __restrict__ hs,         // [B, L, H]
    const float* __restrict__ fc_w,       // [H]
    const int*   __restrict__ clause_len, // [B, D]
    const int*   __restrict__ doc_len,    // [B]
    float*       __restrict__ ws_acc,     // [NTASK][Hc]
    float*       __restrict__ ws_ms)      // [NTASK][2]
{
    const int task = (blockIdx.x * 1619) & (NTASK - 1);   // bijective scatter
    const int bd   = task >> 2;
    const int q    = task & 3;
    const int b    = bd >> 5;
    const int d    = bd & 31;
    const int lane = threadIdx.x;

    // Exclusive prefix sum of clause_len[b, :] in-wave (lanes 0..31 carry data).
    int v = (lane < Dc) ? clause_len[b * Dc + lane] : 0;
    int sum = v;
    #pragma unroll
    for (int s = 1; s < 32; s <<= 1) {
        int o = __shfl_up(sum, s, 64);
        if (lane >= s) sum += o;
    }
    const int vlen = __shfl(v,   d, 64);
    const int off  = __shfl(sum, d, 64) - vlen;
    const int n    = (d < doc_len[b]) ? vlen : 0;
    const int c0   = q * QROWS;
    const int c1   = min(n, c0 + QROWS);

    const int hbase = lane * 4;
    const float4 z4 = {0.f, 0.f, 0.f, 0.f};
    float m = -INFINITY, ssum = 0.0f;
    float4 a0 = z4, a1 = z4, a2 = z4;

    if (c0 < c1) {
        const float4 w0 = *(const float4*)(fc_w + hbase);
        const float4 w1 = *(const float4*)(fc_w + 256 + hbase);
        const float4 w2 = *(const float4*)(fc_w + 512 + hbase);
        // Rows off+c0 .. off+c1-1 are contiguous; off+n-1 <= 2016 < Lc.
        const float* base = hs + (size_t)b * Lc * Hc + (size_t)off * Hc + hbase;

        #define LOADR(c, x0, x1, x2)                                \
            if ((c) < c1) {                                         \
                const float* r_ = base + (size_t)(c) * Hc;          \
                x0 = *(const float4*)(r_);                          \
                x1 = *(const float4*)(r_ + 256);                    \
                x2 = *(const float4*)(r_ + 512);                    \
            } else { x0 = z4; x1 = z4; x2 = z4; }

        float4 A0, A1, A2, B0, B1, B2;
        int c = c0;
        LOADR(c,     A0, A1, A2);
        LOADR(c + 1, B0, B1, B2);
        for (; c < c1; ++c) {
            float4 C0, C1, C2;
            LOADR(c + 2, C0, C1, C2);
            float p = A0.x*w0.x + A0.y*w0.y + A0.z*w0.z + A0.w*w0.w
                    + A1.x*w1.x + A1.y*w1.y + A1.z*w1.z + A1.w*w1.w
                    + A2.x*w2.x + A2.y*w2.y + A2.z*w2.z + A2.w*w2.w;
            #pragma unroll
            for (int s = 32; s > 0; s >>= 1)
                p += __shfl_xor(p, s, 64);
            const float M  = fmaxf(m, p);
            const float sc = __expf(m - M);     // first row: exp(-inf) = 0
            const float e  = __expf(p - M);
            ssum = ssum * sc + e;
            a0.x = fmaf(e, A0.x, a0.x * sc); a0.y = fmaf(e, A0.y, a0.y * sc);
            a0.z = fmaf(e, A0.z, a0.z * sc); a0.w = fmaf(e, A0.w, a0.w * sc);
            a1.x = fmaf(e, A1.x, a1.x * sc); a1.y = fmaf(e, A1.y, a1.y * sc);
            a1.z = fmaf(e, A1.z, a1.z * sc); a1.w = fmaf(e, A1.w, a1.w * sc);
            a2.x = fmaf(e, A2.x, a2.x * sc); a2.y = fmaf(e, A2.y, a2.y * sc);
            a2.z = fmaf(e, A2.z, a2.z * sc); a2.w = fmaf(e, A2.w, a2.w * sc);
            m = M;
            A0 = B0; A1 = B1; A2 = B2;
            B0 = C0; B1 = C1; B2 = C2;
        }
        #undef LOADR
    }

    // Write partial state unconditionally (empty task -> m=-inf, s=0, acc=0).
    float* pa = ws_acc + (size_t)task * Hc;
    *(float4*)(pa + hbase)       = a0;
    *(float4*)(pa + 256 + hbase) = a1;
    *(float4*)(pa + 512 + hbase) = a2;
    if (lane == 0) { ws_ms[task * 2] = m; ws_ms[task * 2 + 1] = ssum; }
}

// K2: one wave per clause merges its 4 partials in fixed order (deterministic).
__global__ __launch_bounds__(256) void k2_merge(
    const float* __restrict__ ws_acc,
    const float* __restrict__ ws_ms,
    float*       __restrict__ out)        // [B, D, H]
{
    const int wave = threadIdx.x >> 6;
    const int lane = threadIdx.x & 63;
    const int bd   = blockIdx.x * 4 + wave;
    const int hbase = lane * 4;
    float* ob = out + (size_t)bd * Hc;

    float mq[NT], sq[NT];
    #pragma unroll
    for (int q = 0; q < NT; ++q) {
        mq[q] = ws_ms[(bd * NT + q) * 2];
        sq[q] = ws_ms[(bd * NT + q) * 2 + 1];
    }
    const float M = fmaxf(fmaxf(mq[0], mq[1]), fmaxf(mq[2], mq[3]));

    if (!(M > -INFINITY)) {
        // n == 0: reference = uniform weights x zeroed sent = exact 0.
        const float4 z4 = {0.f, 0.f, 0.f, 0.f};
        #pragma unroll
        for (int chunk = 0; chunk < 3; ++chunk)
            *(float4*)(ob + chunk * 256 + hbase) = z4;
        return;
    }

    float f[NT], S = 0.0f;
    #pragma unroll
    for (int q = 0; q < NT; ++q) {
        f[q] = __expf(mq[q] - M);            // empty quarter: exp(-inf) = 0
        S += f[q] * sq[q];
    }
    const float rinv = 1.0f / S;             // S > 0 since M finite

    const float* pa = ws_acc + (size_t)bd * NT * Hc;
    #pragma unroll
    for (int chunk = 0; chunk < 3; ++chunk) {
        const int h = chunk * 256 + hbase;
        float4 r = {0.f, 0.f, 0.f, 0.f};
        #pragma unroll
        for (int q = 0; q < NT; ++q) {
            const float4 x = *(const float4*)(pa + q * Hc + h);
            r.x = fmaf(f[q], x.x, r.x);
            r.y = fmaf(f[q], x.y, r.y);
            r.z = fmaf(f[q], x.z, r.z);
            r.w = fmaf(f[q], x.w, r.w);
        }
        r.x *= rinv; r.y *= rinv; r.z *= rinv; r.w *= rinv;
        *(float4*)(ob + h) = r;
    }
}

extern "C" void kernel_launch(void* const* d_in, const int* in_sizes, int n_in,
                              void* d_out, int out_size, void* d_ws, size_t ws_size,
                              hipStream_t stream) {
    const float* hs         = (const float*)d_in[0];  // [B, L, H]
    const float* fc_w       = (const float*)d_in[1];  // [H]
    // d_in[2] = fc_b — constant across the softmax axis, cancels exactly.
    const int*   clause_len = (const int*)d_in[3];    // [B, D]
    const int*   doc_len    = (const int*)d_in[4];    // [B]
    float*       out        = (float*)d_out;          // [B, D, H]

    float* ws_acc = (float*)d_ws;                     // NTASK * Hc floats (12.6 MB)
    float* ws_ms  = ws_acc + (size_t)NTASK * Hc;      // NTASK * 2 floats (32 KB)

    k1_partial<<<NTASK, 64, 0, stream>>>(hs, fc_w, clause_len, doc_len, ws_acc, ws_ms);
    k2_merge<<<Bc * Dc / 4, 256, 0, stream>>>(ws_acc, ws_ms, out);
}

// Round 8
// 21.869 us; speedup vs baseline: 1.1562x; 1.1562x over previous
//
#include <hip/hip_runtime.h>
#include <hip/hip_bf16.h>

#define Bc 32
#define Lc 2048
#define Hc 768
#define Dc 32
#define Cc 64
#define WAVES 4
#define TPB (WAVES * 64)

typedef float f4 __attribute__((ext_vector_type(4)));  // clang vector: nontemporal-ok

// One block (256 threads = 4 waves) per (b, d) clause. Single pass, online
// softmax, 2 rows per step, depth-2 pair pipeline. All 1024 blocks resident
// (4 blocks/CU). Per-wave prefix scan (no startup barrier); nontemporal
// loads/stores for the streamed-once row data and output.
__global__ __launch_bounds__(TPB, 4) void clause_attn_fused(
    const float* __restrict__ hs,         // [B, L, H]
    const float* __restrict__ fc_w,       // [H]
    const int*   __restrict__ clause_len, // [B, D]
    const int*   __restrict__ doc_len,    // [B]
    float*       __restrict__ out)        // [B, D, H]
{
    const int bd   = blockIdx.x;
    const int b    = bd >> 5;     // / Dc
    const int d    = bd & 31;     // % Dc
    const int tid  = threadIdx.x;
    const int lane = tid & 63;
    const int wave = tid >> 6;

    __shared__ float s_m[WAVES];
    __shared__ float s_s[WAVES];
    __shared__ float s_acc[WAVES][Hc];   // 12 KB

    // Every wave: exclusive prefix sum of clause_len[b, :] (lanes 0..31 carry
    // data; one 128B cache line, L1-hot). No barrier needed before loading.
    int v = (lane < Dc) ? clause_len[b * Dc + lane] : 0;
    int sum = v;
    #pragma unroll
    for (int s = 1; s < 32; s <<= 1) {
        int o = __shfl_up(sum, s, 64);
        if (lane >= s) sum += o;
    }
    const int vlen = __shfl(v,   d, 64);
    const int off  = __shfl(sum, d, 64) - vlen;
    const int n    = (d < doc_len[b]) ? vlen : 0;

    float* ob = out + (size_t)bd * Hc;
    const int hbase = lane * 4;
    const f4 z4 = {0.f, 0.f, 0.f, 0.f};

    if (n == 0) {
        // Fully-masked clause: reference = uniform weights x zeroed sent = 0.
        __builtin_nontemporal_store(0.0f, ob + tid);
        __builtin_nontemporal_store(0.0f, ob + tid + 256);
        __builtin_nontemporal_store(0.0f, ob + tid + 512);
        return;
    }

    // Rows are contiguous; off + n - 1 <= 2016 < Lc, no clamping needed.
    const float* base = hs + (size_t)b * Lc * Hc + (size_t)off * Hc + hbase;

    #define LOADROW(c, x0, x1, x2)                                        \
        if ((c) < n) {                                                    \
            const float* r_ = base + (size_t)(c) * Hc;                    \
            x0 = __builtin_nontemporal_load((const f4*)(r_));             \
            x1 = __builtin_nontemporal_load((const f4*)(r_ + 256));       \
            x2 = __builtin_nontemporal_load((const f4*)(r_ + 512));       \
        } else { x0 = z4; x1 = z4; x2 = z4; }

    // Issue the pipeline's first two pairs BEFORE touching fc_w.
    f4 A00, A01, A02, A10, A11, A12;   // compute pair
    f4 B00, B01, B02, B10, B11, B12;   // prefetch depth 1
    int c = wave;
    LOADROW(c,      A00, A01, A02);
    LOADROW(c + 4,  A10, A11, A12);
    LOADROW(c + 8,  B00, B01, B02);
    LOADROW(c + 12, B10, B11, B12);

    const f4 w0 = *(const f4*)(fc_w + hbase);
    const f4 w1 = *(const f4*)(fc_w + 256 + hbase);
    const f4 w2 = *(const f4*)(fc_w + 512 + hbase);

    float m = -INFINITY, ssum = 0.0f;
    f4 a0 = z4, a1 = z4, a2 = z4;

    for (; c < n; c += 8) {
        // Prefetch depth 2: pair(c+16).
        f4 C00, C01, C02, C10, C11, C12;
        LOADROW(c + 16, C00, C01, C02);
        LOADROW(c + 20, C10, C11, C12);

        // Two interleaved dots (row c valid; row c+4 maybe not).
        float p0 = A00.x*w0.x + A00.y*w0.y + A00.z*w0.z + A00.w*w0.w
                 + A01.x*w1.x + A01.y*w1.y + A01.z*w1.z + A01.w*w1.w
                 + A02.x*w2.x + A02.y*w2.y + A02.z*w2.z + A02.w*w2.w;
        float p1 = A10.x*w0.x + A10.y*w0.y + A10.z*w0.z + A10.w*w0.w
                 + A11.x*w1.x + A11.y*w1.y + A11.z*w1.z + A11.w*w1.w
                 + A12.x*w2.x + A12.y*w2.y + A12.z*w2.z + A12.w*w2.w;
        #pragma unroll
        for (int s = 32; s > 0; s >>= 1) {
            p0 += __shfl_xor(p0, s, 64);
            p1 += __shfl_xor(p1, s, 64);
        }
        if (c + 4 >= n) p1 = -INFINITY;    // masked row: e1=0, data already 0

        const float M     = fmaxf(m, fmaxf(p0, p1));   // v_max3
        const float scale = __expf(m - M);             // first pair: exp(-inf)=0
        const float e0    = __expf(p0 - M);
        const float e1    = __expf(p1 - M);
        ssum = ssum * scale + e0 + e1;
        a0.x = fmaf(e1, A10.x, fmaf(e0, A00.x, a0.x * scale));
        a0.y = fmaf(e1, A10.y, fmaf(e0, A00.y, a0.y * scale));
        a0.z = fmaf(e1, A10.z, fmaf(e0, A00.z, a0.z * scale));
        a0.w = fmaf(e1, A10.w, fmaf(e0, A00.w, a0.w * scale));
        a1.x = fmaf(e1, A11.x, fmaf(e0, A01.x, a1.x * scale));
        a1.y = fmaf(e1, A11.y, fmaf(e0, A01.y, a1.y * scale));
        a1.z = fmaf(e1, A11.z, fmaf(e0, A01.z, a1.z * scale));
        a1.w = fmaf(e1, A11.w, fmaf(e0, A01.w, a1.w * scale));
        a2.x = fmaf(e1, A12.x, fmaf(e0, A02.x, a2.x * scale));
        a2.y = fmaf(e1, A12.y, fmaf(e0, A02.y, a2.y * scale));
        a2.z = fmaf(e1, A12.z, fmaf(e0, A02.z, a2.z * scale));
        a2.w = fmaf(e1, A12.w, fmaf(e0, A02.w, a2.w * scale));
        m = M;

        A00 = B00; A01 = B01; A02 = B02; A10 = B10; A11 = B11; A12 = B12;
        B00 = C00; B01 = C01; B02 = C02; B10 = C10; B11 = C11; B12 = C12;
    }
    #undef LOADROW

    // Publish per-wave partial state.
    if (lane == 0) { s_m[wave] = m; s_s[wave] = ssum; }
    *(f4*)&s_acc[wave][hbase]       = a0;
    *(f4*)&s_acc[wave][256 + hbase] = a1;
    *(f4*)&s_acc[wave][512 + hbase] = a2;
    __syncthreads();

    // Merge 4 partials (n >= 1 so wave 0 contributed: M finite, S > 0).
    float Mm = -INFINITY;
    #pragma unroll
    for (int w = 0; w < WAVES; ++w) Mm = fmaxf(Mm, s_m[w]);
    float f[WAVES];
    float S = 0.0f;
    #pragma unroll
    for (int w = 0; w < WAVES; ++w) {
        f[w] = __expf(s_m[w] - Mm);          // idle wave: exp(-inf) = 0
        S += f[w] * s_s[w];
    }
    const float rinv = 1.0f / S;

    #pragma unroll
    for (int chunk = 0; chunk < 3; ++chunk) {
        const int h = chunk * TPB + tid;
        float r = 0.0f;
        #pragma unroll
        for (int w = 0; w < WAVES; ++w) r += f[w] * s_acc[w][h];
        __builtin_nontemporal_store(r * rinv, ob + h);
    }
}

extern "C" void kernel_launch(void* const* d_in, const int* in_sizes, int n_in,
                              void* d_out, int out_size, void* d_ws, size_t ws_size,
                              hipStream_t stream) {
    const float* hs         = (const float*)d_in[0];  // [B, L, H]
    const float* fc_w       = (const float*)d_in[1];  // [H]
    // d_in[2] = fc_b — constant across the softmax axis, cancels exactly.
    const int*   clause_len = (const int*)d_in[3];    // [B, D]
    const int*   doc_len    = (const int*)d_in[4];    // [B]
    float*       out        = (float*)d_out;          // [B, D, H]

    clause_attn_fused<<<Bc * Dc, TPB, 0, stream>>>(hs, fc_w, clause_len, doc_len, out);
}

// Round 9
// 18.789 us; speedup vs baseline: 1.3458x; 1.1640x over previous
//
#include <hip/hip_runtime.h>
#include <hip/hip_bf16.h>

#define Bc 32
#define Lc 2048
#define Hc 768
#define Dc 32
#define Cc 64
#define WAVES 8
#define TPB (WAVES * 64)

// One block (512 threads = 8 waves) per (b, d) clause. Single pass, online
// softmax, 2 rows per step (pair at stride WAVES), depth-2 pair pipeline.
// Per-wave prefix scan (no startup barrier). Plain cached loads/stores
// (nontemporal measured -2us regression in R8).
__global__ __launch_bounds__(TPB, 4) void clause_attn_fused(
    const float* __restrict__ hs,         // [B, L, H]
    const float* __restrict__ fc_w,       // [H]
    const int*   __restrict__ clause_len, // [B, D]
    const int*   __restrict__ doc_len,    // [B]
    float*       __restrict__ out)        // [B, D, H]
{
    const int bd   = blockIdx.x;
    const int b    = bd >> 5;     // / Dc
    const int d    = bd & 31;     // % Dc
    const int tid  = threadIdx.x;
    const int lane = tid & 63;
    const int wave = tid >> 6;

    __shared__ float s_m[WAVES];
    __shared__ float s_s[WAVES];
    __shared__ float s_acc[WAVES][Hc];   // 24 KB

    // Every wave: exclusive prefix sum of clause_len[b, :] (lanes 0..31 carry
    // data; one 128B line, L1-hot). No barrier needed before loading rows.
    int v = (lane < Dc) ? clause_len[b * Dc + lane] : 0;
    int sum = v;
    #pragma unroll
    for (int s = 1; s < 32; s <<= 1) {
        int o = __shfl_up(sum, s, 64);
        if (lane >= s) sum += o;
    }
    const int vlen = __shfl(v,   d, 64);
    const int off  = __shfl(sum, d, 64) - vlen;
    const int n    = (d < doc_len[b]) ? vlen : 0;

    float* ob = out + (size_t)bd * Hc;
    const int hbase = lane * 4;
    const float4 z4 = {0.f, 0.f, 0.f, 0.f};

    if (n == 0) {
        // Fully-masked clause: reference = uniform weights x zeroed sent = 0.
        ob[tid] = 0.0f;
        if (tid < Hc - TPB) ob[TPB + tid] = 0.0f;
        return;
    }

    // Rows are contiguous; off + n - 1 <= 2016 < Lc, no clamping needed.
    const float* base = hs + (size_t)b * Lc * Hc + (size_t)off * Hc + hbase;

    #define LOADROW(c, x0, x1, x2)                                \
        if ((c) < n) {                                            \
            const float* r_ = base + (size_t)(c) * Hc;            \
            x0 = *(const float4*)(r_);                            \
            x1 = *(const float4*)(r_ + 256);                      \
            x2 = *(const float4*)(r_ + 512);                      \
        } else { x0 = z4; x1 = z4; x2 = z4; }

    // Issue the pipeline's first two pairs BEFORE touching fc_w.
    float4 A00, A01, A02, A10, A11, A12;   // compute pair
    float4 B00, B01, B02, B10, B11, B12;   // prefetch depth 1
    int c = wave;
    LOADROW(c,             A00, A01, A02);
    LOADROW(c + WAVES,     A10, A11, A12);
    LOADROW(c + 2 * WAVES, B00, B01, B02);
    LOADROW(c + 3 * WAVES, B10, B11, B12);

    const float4 w0 = *(const float4*)(fc_w + hbase);
    const float4 w1 = *(const float4*)(fc_w + 256 + hbase);
    const float4 w2 = *(const float4*)(fc_w + 512 + hbase);

    float m = -INFINITY, ssum = 0.0f;
    float4 a0 = z4, a1 = z4, a2 = z4;

    for (; c < n; c += 2 * WAVES) {
        // Prefetch depth 2.
        float4 C00, C01, C02, C10, C11, C12;
        LOADROW(c + 4 * WAVES, C00, C01, C02);
        LOADROW(c + 5 * WAVES, C10, C11, C12);

        // Two interleaved dots (row c valid; row c+WAVES maybe not).
        float p0 = A00.x*w0.x + A00.y*w0.y + A00.z*w0.z + A00.w*w0.w
                 + A01.x*w1.x + A01.y*w1.y + A01.z*w1.z + A01.w*w1.w
                 + A02.x*w2.x + A02.y*w2.y + A02.z*w2.z + A02.w*w2.w;
        float p1 = A10.x*w0.x + A10.y*w0.y + A10.z*w0.z + A10.w*w0.w
                 + A11.x*w1.x + A11.y*w1.y + A11.z*w1.z + A11.w*w1.w
                 + A12.x*w2.x + A12.y*w2.y + A12.z*w2.z + A12.w*w2.w;
        #pragma unroll
        for (int s = 32; s > 0; s >>= 1) {
            p0 += __shfl_xor(p0, s, 64);
            p1 += __shfl_xor(p1, s, 64);
        }
        if (c + WAVES >= n) p1 = -INFINITY;   // masked row: e1=0, data already 0

        const float M     = fmaxf(m, fmaxf(p0, p1));   // v_max3
        const float scale = __expf(m - M);             // first pair: exp(-inf)=0
        const float e0    = __expf(p0 - M);
        const float e1    = __expf(p1 - M);
        ssum = ssum * scale + e0 + e1;
        a0.x = fmaf(e1, A10.x, fmaf(e0, A00.x, a0.x * scale));
        a0.y = fmaf(e1, A10.y, fmaf(e0, A00.y, a0.y * scale));
        a0.z = fmaf(e1, A10.z, fmaf(e0, A00.z, a0.z * scale));
        a0.w = fmaf(e1, A10.w, fmaf(e0, A00.w, a0.w * scale));
        a1.x = fmaf(e1, A11.x, fmaf(e0, A01.x, a1.x * scale));
        a1.y = fmaf(e1, A11.y, fmaf(e0, A01.y, a1.y * scale));
        a1.z = fmaf(e1, A11.z, fmaf(e0, A01.z, a1.z * scale));
        a1.w = fmaf(e1, A11.w, fmaf(e0, A01.w, a1.w * scale));
        a2.x = fmaf(e1, A12.x, fmaf(e0, A02.x, a2.x * scale));
        a2.y = fmaf(e1, A12.y, fmaf(e0, A02.y, a2.y * scale));
        a2.z = fmaf(e1, A12.z, fmaf(e0, A02.z, a2.z * scale));
        a2.w = fmaf(e1, A12.w, fmaf(e0, A02.w, a2.w * scale));
        m = M;

        A00 = B00; A01 = B01; A02 = B02; A10 = B10; A11 = B11; A12 = B12;
        B00 = C00; B01 = C01; B02 = C02; B10 = C10; B11 = C11; B12 = C12;
    }
    #undef LOADROW

    // Publish per-wave partial state.
    if (lane == 0) { s_m[wave] = m; s_s[wave] = ssum; }
    *(float4*)&s_acc[wave][hbase]       = a0;
    *(float4*)&s_acc[wave][256 + hbase] = a1;
    *(float4*)&s_acc[wave][512 + hbase] = a2;
    __syncthreads();

    // Merge 8 partials (n >= 1 so wave 0 contributed: M finite, S > 0).
    float Mm = -INFINITY;
    #pragma unroll
    for (int w = 0; w < WAVES; ++w) Mm = fmaxf(Mm, s_m[w]);
    float f[WAVES];
    float S = 0.0f;
    #pragma unroll
    for (int w = 0; w < WAVES; ++w) {
        f[w] = __expf(s_m[w] - Mm);          // idle wave: exp(-inf) = 0
        S += f[w] * s_s[w];
    }
    const float rinv = 1.0f / S;

    float r0 = 0.0f;
    #pragma unroll
    for (int w = 0; w < WAVES; ++w) r0 += f[w] * s_acc[w][tid];
    ob[tid] = r0 * rinv;
    if (tid < Hc - TPB) {
        float r1 = 0.0f;
        #pragma unroll
        for (int w = 0; w < WAVES; ++w) r1 += f[w] * s_acc[w][TPB + tid];
        ob[TPB + tid] = r1 * rinv;
    }
}

extern "C" void kernel_launch(void* const* d_in, const int* in_sizes, int n_in,
                              void* d_out, int out_size, void* d_ws, size_t ws_size,
                              hipStream_t stream) {
    const float* hs         = (const float*)d_in[0];  // [B, L, H]
    const float* fc_w       = (const float*)d_in[1];  // [H]
    // d_in[2] = fc_b — constant across the softmax axis, cancels exactly.
    const int*   clause_len = (const int*)d_in[3];    // [B, D]
    const int*   doc_len    = (const int*)d_in[4];    // [B]
    float*       out        = (float*)d_out;          // [B, D, H]

    clause_attn_fused<<<Bc * Dc, TPB, 0, stream>>>(hs, fc_w, clause_len, doc_len, out);
}